// Round 3
// baseline (521.228 us; speedup 1.0000x reference)
//
#include <hip/hip_runtime.h>
#include <hip/hip_cooperative_groups.h>
#include <math.h>

namespace cg = cooperative_groups;

#define CIN   192
#define BATCH 8
#define HW    65536            // 256*256
#define HW4   16384            // float4 per (b,c) image
#define NBC   (BATCH * CIN)    // 1536
#define NDEG  3

typedef float f4 __attribute__((ext_vector_type(4)));

__device__ __forceinline__ float gelu_exact(float x) {
    return 0.5f * x * (1.0f + erff(x * 0.70710678118654752f));
}
__device__ __forceinline__ float sigmoidf_(float x) {
    return 1.0f / (1.0f + expf(-x));
}

// ---------------- Fused cooperative kernel ----------------
// One block per (b,c) image. Phase 1: own-image mean -> pooled (agent scope).
// grid.sync(). Phase 2: redundant tiny MLP per block -> own mask value.
// Phase 3: re-read own image in REVERSE order (tail is L2/L3-resident), scale,
// NT-store.
__global__ __launch_bounds__(256, 6) void fused_kernel(
    const float* __restrict__ x,
    const float* __restrict__ W1, const float* __restrict__ b1,
    const float* __restrict__ W2, const float* __restrict__ b2,
    const float* __restrict__ M1, const float* __restrict__ bm1,
    const float* __restrict__ M2, const float* __restrict__ bm2,
    float* __restrict__ pooled, float* __restrict__ deg_out,
    float* __restrict__ out)
{
    const int bc = blockIdx.x;           // 0..1535
    const int b  = bc / CIN;
    const int c  = bc % CIN;
    const int t  = threadIdx.x;
    const f4* xp = reinterpret_cast<const f4*>(x) + (size_t)bc * HW4;

    // ---- phase 1: mean of own image ----
    float s = 0.0f;
#pragma unroll 16
    for (int i = 0; i < 64; ++i) {
        f4 v = xp[t + i * 256];
        s += (v.x + v.y) + (v.z + v.w);
    }
    for (int off = 32; off > 0; off >>= 1) s += __shfl_down(s, off, 64);
    __shared__ float ws[4];
    if ((t & 63) == 0) ws[t >> 6] = s;
    __syncthreads();
    if (t == 0) {
        float tot = (ws[0] + ws[1]) + (ws[2] + ws[3]);
        __hip_atomic_store(&pooled[bc], tot * (1.0f / 65536.0f),
                           __ATOMIC_RELEASE, __HIP_MEMORY_SCOPE_AGENT);
    }

    cg::this_grid().sync();

    // ---- phase 2: tiny MLP, redundant per block ----
    __shared__ float sp[CIN];
    __shared__ float sh[128];
    __shared__ float sd[NDEG];
    __shared__ float sm[64];

    if (t < CIN)
        sp[t] = __hip_atomic_load(&pooled[b * CIN + t],
                                  __ATOMIC_ACQUIRE, __HIP_MEMORY_SCOPE_AGENT);
    __syncthreads();

    if (t < 128) {          // h = gelu(pooled @ W1 + b1)
        float a0 = 0.f, a1 = 0.f, a2 = 0.f, a3 = 0.f;
        for (int k = 0; k < CIN; k += 4) {
            a0 += sp[k]     * W1[k * 128 + t];
            a1 += sp[k + 1] * W1[(k + 1) * 128 + t];
            a2 += sp[k + 2] * W1[(k + 2) * 128 + t];
            a3 += sp[k + 3] * W1[(k + 3) * 128 + t];
        }
        sh[t] = gelu_exact(b1[t] + ((a0 + a1) + (a2 + a3)));
    }
    __syncthreads();

    if (t < NDEG) {         // deg = sigmoid(h @ W2 + b2)
        float a0 = 0.f, a1 = 0.f, a2 = 0.f, a3 = 0.f;
        for (int k = 0; k < 128; k += 4) {
            a0 += sh[k]     * W2[k * NDEG + t];
            a1 += sh[k + 1] * W2[(k + 1) * NDEG + t];
            a2 += sh[k + 2] * W2[(k + 2) * NDEG + t];
            a3 += sh[k + 3] * W2[(k + 3) * NDEG + t];
        }
        const float v = sigmoidf_(b2[t] + ((a0 + a1) + (a2 + a3)));
        sd[t] = v;
        if (c == 0) deg_out[b * NDEG + t] = v;   // 8 blocks write deg_prob
    }
    __syncthreads();

    if (t < 64) {           // m = gelu(deg @ M1 + bm1)
        float a = bm1[t];
#pragma unroll
        for (int d = 0; d < NDEG; ++d) a += sd[d] * M1[d * 64 + t];
        sm[t] = gelu_exact(a);
    }
    __syncthreads();

    // mask value for this block's channel (uniform across threads)
    float mv = bm2[c];
#pragma unroll 8
    for (int k = 0; k < 64; ++k) mv += sm[k] * M2[k * CIN + c];
    mv = sigmoidf_(mv);

    // ---- phase 3: scale own image, reverse order (tail is cache-hot) ----
    f4* op = reinterpret_cast<f4*>(out) + (size_t)bc * HW4;
#pragma unroll 4
    for (int i = 63; i >= 0; --i) {
        f4 v = xp[t + i * 256];
        v *= mv;
        __builtin_nontemporal_store(v, op + t + i * 256);
    }
}

// ---------------- Fallback 3-kernel path (proven, R2) ----------------
__global__ __launch_bounds__(256) void pool_kernel(const float* __restrict__ x,
                                                   float* __restrict__ pooled) {
    const int bc = blockIdx.x;
    const f4* xp = reinterpret_cast<const f4*>(x) + (size_t)bc * HW4;
    const int t = threadIdx.x;
    float s = 0.0f;
#pragma unroll 16
    for (int i = 0; i < 64; ++i) {
        f4 v = xp[t + i * 256];
        s += (v.x + v.y) + (v.z + v.w);
    }
    for (int off = 32; off > 0; off >>= 1) s += __shfl_down(s, off, 64);
    __shared__ float ws[4];
    if ((t & 63) == 0) ws[t >> 6] = s;
    __syncthreads();
    if (t == 0) {
        float tot = (ws[0] + ws[1]) + (ws[2] + ws[3]);
        pooled[bc] = tot * (1.0f / 65536.0f);
    }
}

__global__ __launch_bounds__(256) void mlp_kernel(
    const float* __restrict__ pooled,
    const float* __restrict__ W1, const float* __restrict__ b1,
    const float* __restrict__ W2, const float* __restrict__ b2,
    const float* __restrict__ M1, const float* __restrict__ bm1,
    const float* __restrict__ M2, const float* __restrict__ bm2,
    float* __restrict__ mask, float* __restrict__ deg_out) {
    __shared__ float w[CIN * 128];
    __shared__ float sp[NBC];
    __shared__ float sh[BATCH * 128];
    __shared__ float sw2[128 * NDEG];
    __shared__ float sM1[NDEG * 64];
    __shared__ float sd[BATCH * NDEG];
    __shared__ float sm[BATCH * 64];
    const int t = threadIdx.x;

    for (int i = t; i < NBC; i += 256) sp[i] = pooled[i];
    {
        const f4* src = reinterpret_cast<const f4*>(W1);
        f4* dst = reinterpret_cast<f4*>(w);
        for (int i = t; i < (CIN * 128) / 4; i += 256) dst[i] = src[i];
    }
    for (int i = t; i < 128 * NDEG; i += 256) sw2[i] = W2[i];
    if (t < NDEG * 64) sM1[t] = M1[t];
    __syncthreads();

    for (int i = t; i < BATCH * 128; i += 256) {
        const int b = i >> 7, j = i & 127;
        float acc = b1[j];
        const float* prow = &sp[b * CIN];
#pragma unroll 8
        for (int c = 0; c < CIN; ++c) acc += prow[c] * w[c * 128 + j];
        sh[i] = gelu_exact(acc);
    }
    __syncthreads();

    {
        const f4* src = reinterpret_cast<const f4*>(M2);
        f4* dst = reinterpret_cast<f4*>(w);
        for (int i = t; i < (64 * CIN) / 4; i += 256) dst[i] = src[i];
    }

    if (t < BATCH * NDEG) {
        const int b = t / NDEG, d = t % NDEG;
        float acc = b2[d];
        const float* hrow = &sh[b * 128];
#pragma unroll 8
        for (int k = 0; k < 128; ++k) acc += hrow[k] * sw2[k * NDEG + d];
        const float v = sigmoidf_(acc);
        sd[t] = v;
        deg_out[t] = v;
    }
    __syncthreads();

    for (int i = t; i < BATCH * 64; i += 256) {
        const int b = i >> 6, j = i & 63;
        float acc = bm1[j];
#pragma unroll
        for (int d = 0; d < NDEG; ++d) acc += sd[b * NDEG + d] * sM1[d * 64 + j];
        sm[i] = gelu_exact(acc);
    }
    __syncthreads();

    for (int i = t; i < NBC; i += 256) {
        const int b = i / CIN, c = i % CIN;
        float acc = bm2[c];
        const float* mrow = &sm[b * 64];
#pragma unroll 8
        for (int k = 0; k < 64; ++k) acc += mrow[k] * w[k * CIN + c];
        mask[i] = sigmoidf_(acc);
    }
}

__global__ __launch_bounds__(256) void scale_kernel(const float* __restrict__ x,
                                                    const float* __restrict__ mask,
                                                    float* __restrict__ out) {
    const int rb = gridDim.x - 1 - blockIdx.x;
    const int bc = rb >> 3;
    const int chunk = rb & 7;
    const float mval = mask[bc];
    const size_t base = (size_t)bc * HW4 + (size_t)chunk * 2048;
    const f4* xp = reinterpret_cast<const f4*>(x) + base;
    f4* op = reinterpret_cast<f4*>(out) + base;
    const int t = threadIdx.x;
#pragma unroll
    for (int i = 0; i < 8; ++i) {
        f4 v = xp[t + i * 256];
        v *= mval;
        __builtin_nontemporal_store(v, op + t + i * 256);
    }
}

extern "C" void kernel_launch(void* const* d_in, const int* in_sizes, int n_in,
                              void* d_out, int out_size, void* d_ws, size_t ws_size,
                              hipStream_t stream) {
    const float* x   = (const float*)d_in[0];
    const float* W1  = (const float*)d_in[1];
    const float* b1  = (const float*)d_in[2];
    const float* W2  = (const float*)d_in[3];
    const float* b2  = (const float*)d_in[4];
    const float* M1  = (const float*)d_in[5];
    const float* bm1 = (const float*)d_in[6];
    const float* M2  = (const float*)d_in[7];
    const float* bm2 = (const float*)d_in[8];

    float* out0    = (float*)d_out;
    float* deg_out = out0 + (size_t)NBC * HW;

    float* pooled = (float*)d_ws;        // 1536 floats
    float* mask   = pooled + NBC;        // 1536 floats (fallback only)

    // Try the fused cooperative kernel first.
    void* args[] = {
        (void*)&x, (void*)&W1, (void*)&b1, (void*)&W2, (void*)&b2,
        (void*)&M1, (void*)&bm1, (void*)&M2, (void*)&bm2,
        (void*)&pooled, (void*)&deg_out, (void*)&out0
    };
    hipError_t err = hipLaunchCooperativeKernel(
        (const void*)fused_kernel, dim3(NBC), dim3(256), args, 0, stream);

    if (err != hipSuccess) {
        // Fallback: proven 3-kernel path.
        pool_kernel<<<NBC, 256, 0, stream>>>(x, pooled);
        mlp_kernel<<<1, 256, 0, stream>>>(pooled, W1, b1, W2, b2, M1, bm1, M2, bm2,
                                          mask, deg_out);
        scale_kernel<<<NBC * 8, 256, 0, stream>>>(x, mask, out0);
    }
}

// Round 4
// 213.258 us; speedup vs baseline: 2.4441x; 2.4441x over previous
//
#include <hip/hip_runtime.h>
#include <math.h>

#define CIN    192
#define BATCH  8
#define HW     65536            // 256*256
#define HW4    16384            // float4 per (b,c) image
#define NBC    (BATCH * CIN)    // 1536
#define NDEG   3

// Pipeline grouping: 2 groups x 4 batches. Each group's x slice is
// 4*192*256*256*4B = 201 MB < 256 MB L3, so scale_g re-reads it from L3.
#define BPG    4                // batches per group
#define BCPG   (BPG * CIN)      // 768 images per group

typedef float f4 __attribute__((ext_vector_type(4)));

__device__ __forceinline__ float gelu_exact(float x) {
    return 0.5f * x * (1.0f + erff(x * 0.70710678118654752f));
}
__device__ __forceinline__ float sigmoidf_(float x) {
    return 1.0f / (1.0f + expf(-x));
}

// pooled[bc] = mean over H*W of x[bc,:,:] for one group of batches.
// Normal (caching) loads: primes L3 with this group's slice.
__global__ __launch_bounds__(256) void pool_kernel(const float* __restrict__ x,
                                                   float* __restrict__ pooled,
                                                   int bc_base) {
    const int bc = bc_base + blockIdx.x;
    const f4* xp = reinterpret_cast<const f4*>(x) + (size_t)bc * HW4;
    const int t = threadIdx.x;
    float s = 0.0f;
#pragma unroll 16
    for (int i = 0; i < 64; ++i) {
        f4 v = xp[t + i * 256];
        s += (v.x + v.y) + (v.z + v.w);
    }
    for (int off = 32; off > 0; off >>= 1) s += __shfl_down(s, off, 64);
    __shared__ float ws[4];
    if ((t & 63) == 0) ws[t >> 6] = s;
    __syncthreads();
    if (t == 0) {
        float tot = (ws[0] + ws[1]) + (ws[2] + ws[3]);
        pooled[bc] = tot * (1.0f / 65536.0f);
    }
}

// MLP for one group: one block per batch (grid = BPG). Weights come from
// global (L2-shared across the 4 blocks; tiny).
__global__ __launch_bounds__(256) void mlp_kernel(
    const float* __restrict__ pooled,
    const float* __restrict__ W1, const float* __restrict__ b1,
    const float* __restrict__ W2, const float* __restrict__ b2,
    const float* __restrict__ M1, const float* __restrict__ bm1,
    const float* __restrict__ M2, const float* __restrict__ bm2,
    float* __restrict__ mask, float* __restrict__ deg_out, int b_base) {
    const int b = b_base + blockIdx.x;
    const int t = threadIdx.x;
    __shared__ float sp[CIN];
    __shared__ float sh[128];
    __shared__ float sd[NDEG];
    __shared__ float sm[64];

    if (t < CIN) sp[t] = pooled[b * CIN + t];
    __syncthreads();

    if (t < 128) {              // h = gelu(pooled @ W1 + b1)
        float a0 = 0.f, a1 = 0.f, a2 = 0.f, a3 = 0.f;
#pragma unroll 8
        for (int k = 0; k < CIN; k += 4) {
            a0 += sp[k]     * W1[k * 128 + t];
            a1 += sp[k + 1] * W1[(k + 1) * 128 + t];
            a2 += sp[k + 2] * W1[(k + 2) * 128 + t];
            a3 += sp[k + 3] * W1[(k + 3) * 128 + t];
        }
        sh[t] = gelu_exact(b1[t] + ((a0 + a1) + (a2 + a3)));
    }
    __syncthreads();

    if (t < NDEG) {             // deg = sigmoid(h @ W2 + b2)
        float a0 = 0.f, a1 = 0.f, a2 = 0.f, a3 = 0.f;
#pragma unroll 8
        for (int k = 0; k < 128; k += 4) {
            a0 += sh[k]     * W2[k * NDEG + t];
            a1 += sh[k + 1] * W2[(k + 1) * NDEG + t];
            a2 += sh[k + 2] * W2[(k + 2) * NDEG + t];
            a3 += sh[k + 3] * W2[(k + 3) * NDEG + t];
        }
        const float v = sigmoidf_(b2[t] + ((a0 + a1) + (a2 + a3)));
        sd[t] = v;
        deg_out[b * NDEG + t] = v;
    }
    __syncthreads();

    if (t < 64) {               // m = gelu(deg @ M1 + bm1)
        float a = bm1[t];
#pragma unroll
        for (int d = 0; d < NDEG; ++d) a += sd[d] * M1[d * 64 + t];
        sm[t] = gelu_exact(a);
    }
    __syncthreads();

    if (t < CIN) {              // mask = sigmoid(m @ M2 + bm2)
        float a = bm2[t];
#pragma unroll 8
        for (int k = 0; k < 64; ++k) a += sm[k] * M2[k * CIN + t];
        mask[b * CIN + t] = sigmoidf_(a);
    }
}

// out[bc,:,:] = x[bc,:,:] * mask[bc] for one group.
// Reverse order within the group (most-recently-pooled first), normal
// cacheable x loads (hit L3), NT stores (don't evict the group's x).
__global__ __launch_bounds__(256) void scale_kernel(const float* __restrict__ x,
                                                    const float* __restrict__ mask,
                                                    float* __restrict__ out,
                                                    int bc_base) {
    const int rb = gridDim.x - 1 - blockIdx.x;       // reversed
    const int bc = bc_base + (rb >> 3);
    const int chunk = rb & 7;
    const float mval = mask[bc];
    const size_t base = (size_t)bc * HW4 + (size_t)chunk * 2048;
    const f4* xp = reinterpret_cast<const f4*>(x) + base;
    f4* op = reinterpret_cast<f4*>(out) + base;
    const int t = threadIdx.x;
#pragma unroll
    for (int i = 0; i < 8; ++i) {
        f4 v = xp[t + i * 256];
        v *= mval;
        __builtin_nontemporal_store(v, op + t + i * 256);
    }
}

extern "C" void kernel_launch(void* const* d_in, const int* in_sizes, int n_in,
                              void* d_out, int out_size, void* d_ws, size_t ws_size,
                              hipStream_t stream) {
    const float* x   = (const float*)d_in[0];
    const float* W1  = (const float*)d_in[1];
    const float* b1  = (const float*)d_in[2];
    const float* W2  = (const float*)d_in[3];
    const float* b2  = (const float*)d_in[4];
    const float* M1  = (const float*)d_in[5];
    const float* bm1 = (const float*)d_in[6];
    const float* M2  = (const float*)d_in[7];
    const float* bm2 = (const float*)d_in[8];

    float* out0    = (float*)d_out;                  // 8*192*256*256 floats
    float* deg_out = out0 + (size_t)NBC * HW;        // 24 floats

    float* pooled = (float*)d_ws;                    // 1536 floats
    float* mask   = pooled + NBC;                    // 1536 floats

    for (int g = 0; g < BATCH / BPG; ++g) {
        const int b_base  = g * BPG;
        const int bc_base = b_base * CIN;
        pool_kernel<<<BCPG, 256, 0, stream>>>(x, pooled, bc_base);
        mlp_kernel<<<BPG, 256, 0, stream>>>(pooled, W1, b1, W2, b2,
                                            M1, bm1, M2, bm2,
                                            mask, deg_out, b_base);
        scale_kernel<<<BCPG * 8, 256, 0, stream>>>(x, mask, out0, bc_base);
    }
}